// Round 21
// baseline (69.278 us; speedup 1.0000x reference)
//
#include <hip/hip_runtime.h>
#include <math.h>

// HoltWintersDecomposition: x (8192, 2048) f32, sequential per-row recurrence.
// r21 = r20 + producer-side deferred y (consumer diet):
//   r20 evidence: cutting the serial cycle by ~8cy moved nothing -> producer
//   latency is NOT the binder; the consumer path (serialized per-tile x global
//   loads + 8 rcps/it + store drain) is the suspect.
//   The one-rcp chain already computes u_t = rcp(D_{t-1}) -> y_{t-1} =
//   x_{t-1} * u_t is ONE extra off-cycle mul (r15's deferred-y, validated).
//   Producer: +1 mul + 1/3 more ds_write per step (fits in the rcp shadow).
//   Consumers: NO global x loads, only s = D*rcp(l) reconstruction + stores.
//   Tile-end finalization: y[63] = xprev * rcp(D) off-chain (bitwise equal to
//   next step's u). t=0: y0 = x0*rcp(D0) via the t=1 step's u.
// Structure (r18-r20): 256 blocks x 32 rows; wave0 producer (lanes 0..31,
// full-tile x register prefetch, 1-tile lead); waves 1-2 consumers;
// 1 barrier/tile. Minimal cycle: u=rcp(D) -> lte'=fma(m,u,cl) ->
// D'=fma(EPSg,lte',cD); m,cl,pre,cD parallel with the rcp.
// Lessons: r6 parallel-in-time broken (s ~ 20*EPS); r9 producer loads need
// >= 1-tile lead; r4/r12/r17 never pack 2 chains into one wave.

constexpr int   T    = 2048;
constexpr int   B    = 8192;
constexpr int   RPB  = 32;        // rows per block
constexpr int   TT   = 64;        // steps per tile
constexpr int   NTI  = T / TT;    // 32 tiles
constexpr int   LSX  = 68;        // LDS stride words: 272B rows, 16B-aligned
constexpr float EPS  = 1e-8f;

__global__ __launch_bounds__(192, 1)
void hw_kernel(const float* __restrict__ x,
               const float* __restrict__ pla,
               const float* __restrict__ plg,
               float* __restrict__ out)
{
    __shared__ alignas(16) float LT[2][RPB][LSX];   // lte = l + EPS
    __shared__ alignas(16) float DT[2][RPB][LSX];   // D = lte * ste
    __shared__ alignas(16) float YT[2][RPB][LSX];   // y = x * rcp(D)

    const int tid  = threadIdx.x;
    const int wid  = tid >> 6;        // 0 = producer, 1..2 = consumers
    const int lane = tid & 63;
    const int row0 = blockIdx.x * RPB;

    const float alpha = 1.0f / (1.0f + expf(-pla[0]));
    const float gamma = 1.0f / (1.0f + expf(-plg[0]));
    const float oma = 1.0f - alpha, omg = 1.0f - gamma;
    const float EPSa = EPS * alpha;
    const float EPSg = EPS * gamma;

    float* __restrict__ lout = out;
    float* __restrict__ sout = out + (size_t)B * T;
    float* __restrict__ yout = out + (size_t)2 * B * T;

    // store-phase lane mapping
    const int cr = lane >> 4;          // 0..3
    const int cc = (lane & 15) << 2;   // 0,4,...,60

    // consumer: l,D,y from LDS; s = D*rcp(l); no global x loads
    auto store_tile = [&](int m, int itlo, int ithi) {
        const int bsel = m & 1;
        const int t0 = m * TT;
        for (int it = itlo; it < ithi; ++it) {
            const int r = 4 * it + cr;
            const size_t g = (size_t)(row0 + r) * T + t0 + cc;
            const float4 vl = *reinterpret_cast<const float4*>(&LT[bsel][r][cc]);
            const float4 vd = *reinterpret_cast<const float4*>(&DT[bsel][r][cc]);
            const float4 vy = *reinterpret_cast<const float4*>(&YT[bsel][r][cc]);
            float4 vs;
            vs.x = vd.x * __builtin_amdgcn_rcpf(vl.x);
            vs.y = vd.y * __builtin_amdgcn_rcpf(vl.y);
            vs.z = vd.z * __builtin_amdgcn_rcpf(vl.z);
            vs.w = vd.w * __builtin_amdgcn_rcpf(vl.w);
            *reinterpret_cast<float4*>(&lout[g]) = vl;
            *reinterpret_cast<float4*>(&sout[g]) = vs;
            *reinterpret_cast<float4*>(&yout[g]) = vy;
        }
    };

    if (wid == 0) {
        // ================= producer =================
        const bool act = lane < RPB;
        const float* __restrict__ xrow = x + (size_t)(row0 + (act ? lane : 0)) * T;

        float lte = 0.0f;   // l + EPS
        float D   = 1.0f;   // lte * ste
        float xpv = 0.0f;   // x_{t-1}, carried for deferred y
        float4 XA[16], XB[16];

        auto loadX = [&](float4* Xb, int k) {
            const float* p = xrow + k * TT;
            #pragma unroll
            for (int i = 0; i < 16; ++i)
                Xb[i] = *reinterpret_cast<const float4*>(p + 4 * i);
        };

        // minimal cycle + deferred y: u = rcp(D); y_{t-1} = xpv*u (off-cycle);
        // lte' = fma(m,u,cl); D' = fma(EPSg,lte',cD)
        auto do_step = [&](float xt, float& lo, float& dsto, float& yprev) {
            const float ax  = alpha * xt;                       // off-chain
            const float gx  = gamma * xt;                       // off-chain
            const float m   = ax * lte;                         // || with rcp
            const float cl  = __builtin_fmaf(oma, lte, EPSa);   // || with rcp
            const float pre = __builtin_fmaf(oma, D, ax);       // || with rcp
            const float cD  = __builtin_fmaf(omg, pre, gx);     // || with rcp
            const float u   = __builtin_amdgcn_rcpf(D);         // chain
            yprev = xpv * u;                                    // off-cycle
            const float ltn = __builtin_fmaf(m, u, cl);         // chain
            const float Dn  = __builtin_fmaf(EPSg, ltn, cD);    // chain
            lo = ltn; dsto = Dn;
            lte = ltn; D = Dn; xpv = xt;
        };

        auto compute_tile = [&](const float4* Xb, int k, bool first) {
            const int bsel = k & 1;
            float4 yv;
            #pragma unroll
            for (int g = 0; g < 16; ++g) {
                const float4 xv = Xb[g];
                float4 lv, dv;
                if (first && g == 0) {
                    // t == 0: l0 = x0, s0 = 1 (primed); y0 via next step's u
                    lte = xv.x + EPS;
                    D   = lte * (1.0f + EPS);
                    xpv = xv.x;
                    lv.x = lte; dv.x = D;
                    do_step(xv.y, lv.y, dv.y, yv.x);   // yv.x = y0
                } else {
                    do_step(xv.x, lv.x, dv.x, yv.w);   // y[4g-1] -> slot3
                    if (g > 0)
                        *reinterpret_cast<float4*>(&YT[bsel][lane][4 * (g - 1)]) = yv;
                    do_step(xv.y, lv.y, dv.y, yv.x);   // y[4g]
                }
                do_step(xv.z, lv.z, dv.z, yv.y);       // y[4g+1]
                do_step(xv.w, lv.w, dv.w, yv.z);       // y[4g+2]
                *reinterpret_cast<float4*>(&LT[bsel][lane][4 * g]) = lv;
                *reinterpret_cast<float4*>(&DT[bsel][lane][4 * g]) = dv;
            }
            // finalize y[63] = xpv * rcp(D): bitwise-equal to next step's u
            yv.w = xpv * __builtin_amdgcn_rcpf(D);
            *reinterpret_cast<float4*>(&YT[bsel][lane][60]) = yv;
        };

        if (act) { loadX(XA, 0); loadX(XB, 1); }
        if (act) compute_tile(XA, 0, true);     // one-time vmcnt wait on XA
        __syncthreads();

        #pragma unroll 1
        for (int k = 1; k < NTI - 1; k += 2) {
            if (act) { loadX(XA, k + 1); compute_tile(XB, k, false); }
            __syncthreads();
            if (act) { loadX(XB, k + 2); compute_tile(XA, k + 1, false); }
            __syncthreads();
        }
        if (act) compute_tile(XB, NTI - 1, false);
        __syncthreads();
    } else {
        // ================= consumers: stores + s reconstruction ===========
        const int lo = (wid - 1) * 4;            // wave1: 0..3, wave2: 4..7
        #pragma unroll 1
        for (int k = 0; k < NTI; ++k) {
            if (k > 0) store_tile(k - 1, lo, lo + 4);
            __syncthreads();
        }
    }

    // epilogue: tile 31 (buffer 1), all three waves split the 8 store groups
    {
        const int lo = (wid == 0) ? 0 : (wid == 1) ? 2 : 5;
        const int hi = (wid == 0) ? 2 : (wid == 1) ? 5 : 8;
        store_tile(NTI - 1, lo, hi);
    }
}

extern "C" void kernel_launch(void* const* d_in, const int* in_sizes, int n_in,
                              void* d_out, int out_size, void* d_ws, size_t ws_size,
                              hipStream_t stream) {
    const float* x   = (const float*)d_in[0];
    const float* pla = (const float*)d_in[1];
    const float* plg = (const float*)d_in[2];
    float* out = (float*)d_out;

    dim3 grid(B / RPB);    // 256 blocks -> one producer + 2 consumers per CU
    dim3 block(192);       // wave0 producer (32 rows), waves 1-2 consumers
    hw_kernel<<<grid, block, 0, stream>>>(x, pla, plg, out);
}

// Round 22
// 62.719 us; speedup vs baseline: 1.1046x; 1.1046x over previous
//
#include <hip/hip_runtime.h>
#include <math.h>

// HoltWintersDecomposition: x (8192, 2048) f32, sequential per-row recurrence.
// r22 = r19 (best, 61.9us) + counted barriers (lgkmcnt-only, global ops fly):
//   __syncthreads() emits s_waitcnt vmcnt(0) lgkmcnt(0) + s_barrier -> every
//   tile each consumer stalls until its 12 global stores RETIRE, and the
//   producer until its prefetch loads land. But the only cross-wave handoff is
//   through LDS: global stores are write-once/never-read, global x loads are
//   register-tracked in-wave. So the barrier only needs lgkmcnt(0).
//   Raw __builtin_amdgcn_s_barrier() + inline-asm lgkmcnt(0) (+ sched_barrier
//   fences, rule #18) lets the store stream drain continuously across tiles.
//   Tile: max(producer ~2100cy, consumer ~600cy + async write share ~2400cy).
// Arithmetic = r19 exactly (one-rcp product-state; r20 reassoc was neutral,
// r21 producer-y regressed -> producer is ISSUE-bound; r19 split is optimal):
//   producer: lte' = fma(ax,v,cl); D' = fma(omg,pre,K); u = rcp(D'); v' = lte'*u
//   consumers: s = D*rcp(l), y = x*rcp(D).
// Structure: 256 blocks x 32 rows; wave0 producer (lanes 0..31, full-tile x
// register prefetch, 1-tile lead); waves 1-2 consumers; 1 counted barrier/tile.
// Lessons: r6 parallel-in-time broken (s ~ 20*EPS); r9 producer loads need
// >= 1-tile lead; r4/r12/r17 never pack 2 chains into one wave.

constexpr int   T    = 2048;
constexpr int   B    = 8192;
constexpr int   RPB  = 32;        // rows per block
constexpr int   TT   = 64;        // steps per tile
constexpr int   NTI  = T / TT;    // 32 tiles
constexpr int   LSX  = 68;        // LDS stride words: 272B rows, 16B-aligned
constexpr float EPS  = 1e-8f;

// barrier that drains ONLY LDS counters; global loads/stores stay in flight
__device__ __forceinline__ void lds_barrier() {
    __builtin_amdgcn_sched_barrier(0);
    asm volatile("s_waitcnt lgkmcnt(0)" ::: "memory");
    __builtin_amdgcn_s_barrier();
    __builtin_amdgcn_sched_barrier(0);
}

__global__ __launch_bounds__(192, 1)
void hw_kernel(const float* __restrict__ x,
               const float* __restrict__ pla,
               const float* __restrict__ plg,
               float* __restrict__ out)
{
    __shared__ alignas(16) float LT[2][RPB][LSX];   // lte = l + EPS
    __shared__ alignas(16) float DT[2][RPB][LSX];   // D = lte * ste

    const int tid  = threadIdx.x;
    const int wid  = tid >> 6;        // 0 = producer, 1..2 = consumers
    const int lane = tid & 63;
    const int row0 = blockIdx.x * RPB;

    const float alpha = 1.0f / (1.0f + expf(-pla[0]));
    const float gamma = 1.0f / (1.0f + expf(-plg[0]));
    const float oma = 1.0f - alpha, omg = 1.0f - gamma;
    const float EPSa = EPS * alpha;
    const float EPSg = EPS * gamma;

    float* __restrict__ lout = out;
    float* __restrict__ sout = out + (size_t)B * T;
    float* __restrict__ yout = out + (size_t)2 * B * T;

    // store-phase lane mapping
    const int cr = lane >> 4;          // 0..3
    const int cc = (lane & 15) << 2;   // 0,4,...,60

    // consumer: l from LDS; s = D*rcp(l); y = x*rcp(D)
    auto store_tile = [&](int m, int itlo, int ithi) {
        const int bsel = m & 1;
        const int t0 = m * TT;
        #pragma unroll
        for (int it = itlo; it < ithi; ++it) {
            const int r = 4 * it + cr;
            const size_t g = (size_t)(row0 + r) * T + t0 + cc;
            const float4 vl = *reinterpret_cast<const float4*>(&LT[bsel][r][cc]);
            const float4 vd = *reinterpret_cast<const float4*>(&DT[bsel][r][cc]);
            const float4 xv = *reinterpret_cast<const float4*>(&x[g]);
            float4 vs, vy;
            vs.x = vd.x * __builtin_amdgcn_rcpf(vl.x);
            vs.y = vd.y * __builtin_amdgcn_rcpf(vl.y);
            vs.z = vd.z * __builtin_amdgcn_rcpf(vl.z);
            vs.w = vd.w * __builtin_amdgcn_rcpf(vl.w);
            vy.x = xv.x * __builtin_amdgcn_rcpf(vd.x);
            vy.y = xv.y * __builtin_amdgcn_rcpf(vd.y);
            vy.z = xv.z * __builtin_amdgcn_rcpf(vd.z);
            vy.w = xv.w * __builtin_amdgcn_rcpf(vd.w);
            *reinterpret_cast<float4*>(&lout[g]) = vl;
            *reinterpret_cast<float4*>(&sout[g]) = vs;
            *reinterpret_cast<float4*>(&yout[g]) = vy;
        }
    };

    if (wid == 0) {
        // ================= producer =================
        const bool act = lane < RPB;
        const float* __restrict__ xrow = x + (size_t)(row0 + (act ? lane : 0)) * T;

        float lte = 0.0f;   // l + EPS
        float D   = 1.0f;   // lte * ste
        float v   = 1.0f;   // rcp(ste), carried as lte*rcp(D)
        float4 XA[16], XB[16];

        auto loadX = [&](float4* Xb, int k) {
            const float* p = xrow + k * TT;
            #pragma unroll
            for (int i = 0; i < 16; ++i)
                Xb[i] = *reinterpret_cast<const float4*>(p + 4 * i);
        };

        // ONE-rcp step (r19): cycle D -> u(rcp) -> v(mul) -> lte'(fma) -> K -> D'
        auto do_step = [&](float xt, float& lo, float& dsto) {
            const float ax  = alpha * xt;                       // off-chain
            const float gx  = gamma * xt;                       // off-chain
            const float cl  = __builtin_fmaf(oma, lte, EPSa);   // off-chain
            const float pre = __builtin_fmaf(oma, D, ax);       // off-chain
            const float ltn = __builtin_fmaf(ax, v, cl);        // chain
            const float K   = __builtin_fmaf(EPSg, ltn, gx);    // chain
            const float Dn  = __builtin_fmaf(omg, pre, K);      // chain
            const float un  = __builtin_amdgcn_rcpf(Dn);        // chain (one rcp)
            const float vn  = ltn * un;                         // chain
            lo = ltn; dsto = Dn;
            lte = ltn; D = Dn; v = vn;
        };

        auto compute_tile = [&](const float4* Xb, int k, bool first) {
            const int bsel = k & 1;
            #pragma unroll
            for (int g = 0; g < 16; ++g) {
                const float4 xv = Xb[g];
                float4 lv, dv;
                if (first && g == 0) {
                    // t == 0: l0 = x0, s0 = 1 (primed): lte = x0+e, ste = 1+e
                    lte = xv.x + EPS;
                    const float ste0 = 1.0f + EPS;
                    D = lte * ste0;
                    v = lte * __builtin_amdgcn_rcpf(D);
                    lv.x = lte; dv.x = D;
                    do_step(xv.y, lv.y, dv.y);
                    do_step(xv.z, lv.z, dv.z);
                    do_step(xv.w, lv.w, dv.w);
                } else {
                    do_step(xv.x, lv.x, dv.x);
                    do_step(xv.y, lv.y, dv.y);
                    do_step(xv.z, lv.z, dv.z);
                    do_step(xv.w, lv.w, dv.w);
                }
                *reinterpret_cast<float4*>(&LT[bsel][lane][4 * g]) = lv;
                *reinterpret_cast<float4*>(&DT[bsel][lane][4 * g]) = dv;
            }
        };

        if (act) { loadX(XA, 0); loadX(XB, 1); }
        if (act) compute_tile(XA, 0, true);     // one-time vmcnt wait on XA
        lds_barrier();

        #pragma unroll 1
        for (int k = 1; k < NTI - 1; k += 2) {
            if (act) { loadX(XA, k + 1); compute_tile(XB, k, false); }
            lds_barrier();
            if (act) { loadX(XB, k + 2); compute_tile(XA, k + 1, false); }
            lds_barrier();
        }
        if (act) compute_tile(XB, NTI - 1, false);
        lds_barrier();
    } else {
        // ================= consumers: stores + s/y, half tile each ========
        const int lo = (wid - 1) * 4;            // wave1: 0..3, wave2: 4..7
        #pragma unroll 1
        for (int k = 0; k < NTI; ++k) {
            if (k > 0) store_tile(k - 1, lo, lo + 4);
            lds_barrier();
        }
    }

    // epilogue: tile 31 (buffer 1), all three waves split the 8 store groups
    {
        const int lo = (wid == 0) ? 0 : (wid == 1) ? 2 : 5;
        const int hi = (wid == 0) ? 2 : (wid == 1) ? 5 : 8;
        store_tile(NTI - 1, lo, hi);
    }
}

extern "C" void kernel_launch(void* const* d_in, const int* in_sizes, int n_in,
                              void* d_out, int out_size, void* d_ws, size_t ws_size,
                              hipStream_t stream) {
    const float* x   = (const float*)d_in[0];
    const float* pla = (const float*)d_in[1];
    const float* plg = (const float*)d_in[2];
    float* out = (float*)d_out;

    dim3 grid(B / RPB);    // 256 blocks -> one producer + 2 consumers per CU
    dim3 block(192);       // wave0 producer (32 rows), waves 1-2 consumers
    hw_kernel<<<grid, block, 0, stream>>>(x, pla, plg, out);
}